// Round 24
// baseline (206.625 us; speedup 1.0000x reference)
//
#include <hip/hip_runtime.h>

#define NFEAT   128
#define NHID    64
#define NLAYER  3
#define NNODES  50000
#define NEDGES  800000
#define NGRAPHS 512
#define BN_EPS  1e-5f
#define MLPB    1563          // virtual blocks for gemm/mlp/bnh (ceil(50000/32))
#define CAP     64            // fixed CSR row capacity (max deg ~45 for Poisson(16))
#define PADW    68            // u16 row pad (136B rows, 8B aligned)
#define FILLB   2048          // fill blocks (8 ranges x 256 chunks)
#define SETUPB  51            // setup blocks (wt cvt 12288 + gstart 513)

typedef unsigned short u16;
typedef __attribute__((ext_vector_type(8))) short bf8;     // 8 bf16 (4 VGPRs)
typedef __attribute__((ext_vector_type(4))) float f32x4;

__device__ inline float b2f(u16 v) { return __uint_as_float(((unsigned)v) << 16); }
__device__ inline u16 f2b(float f) {
    unsigned u = __float_as_uint(f);
    return (u16)((u + 0x7FFF + ((u >> 16) & 1)) >> 16);   // RN-even
}
__device__ inline bf8 ldb8(const u16* p) {   // 16B from 8B-aligned LDS
    union { uint2 a[2]; bf8 v; } u;
    u.a[0] = *(const uint2*)p;
    u.a[1] = *(const uint2*)(p + 4);
    return u.v;
}
__device__ inline bf8 ldb8g(const u16* p) {  // 16B from 16B-aligned global
    union { uint4 a; bf8 v; } u;
    u.a = *(const uint4*)p;
    return u.v;
}
__device__ inline void add4(float* a, const uint2 v) {   // a[0..3] += bf16x4
    a[0] += __uint_as_float(v.x << 16);
    a[1] += __uint_as_float(v.x & 0xFFFF0000u);
    a[2] += __uint_as_float(v.y << 16);
    a[3] += __uint_as_float(v.y & 0xFFFF0000u);
}
__device__ inline void unp4(float* a, const uint2 v) {
    a[0] = __uint_as_float(v.x << 16);
    a[1] = __uint_as_float(v.x & 0xFFFF0000u);
    a[2] = __uint_as_float(v.y << 16);
    a[3] = __uint_as_float(v.y & 0xFFFF0000u);
}
__device__ inline void unp8(float* a, const uint4 v) {
    a[0] = __uint_as_float(v.x << 16);
    a[1] = __uint_as_float(v.x & 0xFFFF0000u);
    a[2] = __uint_as_float(v.y << 16);
    a[3] = __uint_as_float(v.y & 0xFFFF0000u);
    a[4] = __uint_as_float(v.z << 16);
    a[5] = __uint_as_float(v.z & 0xFFFF0000u);
    a[6] = __uint_as_float(v.w << 16);
    a[7] = __uint_as_float(v.w & 0xFFFF0000u);
}
__device__ inline uint2 pack4(float a, float b, float c, float d) {
    uint2 r;
    r.x = (unsigned)f2b(a) | ((unsigned)f2b(b) << 16);
    r.y = (unsigned)f2b(c) | ((unsigned)f2b(d) << 16);
    return r;
}

// ---------------------------------------------------------------- build + setup + MFMA input GEMM, one dispatch (no fences)
__global__ __launch_bounds__(256) void k_buildgemm(const int* __restrict__ ei,
                                                   int* __restrict__ deg,
                                                   u16* __restrict__ col,
                                                   const float* __restrict__ Wt,
                                                   const float* __restrict__ W1,
                                                   const float* __restrict__ W2,
                                                   const int* __restrict__ batch,
                                                   u16* __restrict__ wt,
                                                   int* __restrict__ gstart,
                                                   const float* __restrict__ x,
                                                   const float* __restrict__ bt,
                                                   u16* __restrict__ zout,
                                                   float* __restrict__ partials) {
    __shared__ u16 sx[32][132];
    __shared__ float ps[128];
    int tid = threadIdx.x;
    if (blockIdx.x < FILLB) {
        // ---- CSR fill (8x ILP, XCD-range partitioned) ----
        int rangeId = blockIdx.x & 7, chunk = blockIdx.x >> 3;
        int lo = rangeId * (NNODES / 8), hi = lo + (NNODES / 8);
        int ebeg = chunk * (NEDGES / 256), eend = ebeg + (NEDGES / 256);
        int e = ebeg + tid;
        for (; e + 7 * 256 < eend; e += 8 * 256) {
            int d[8];
#pragma unroll
            for (int i = 0; i < 8; ++i) d[i] = ei[NEDGES + e + i * 256];
#pragma unroll
            for (int i = 0; i < 8; ++i) {
                if (d[i] >= lo && d[i] < hi) {
                    int s = atomicAdd(&deg[d[i]], 1);
                    if (s < CAP) col[d[i] * CAP + s] = (u16)ei[e + i * 256];
                }
            }
        }
        for (; e < eend; e += 256) {
            int dst = ei[NEDGES + e];
            if (dst >= lo && dst < hi) {
                int s = atomicAdd(&deg[dst], 1);
                if (s < CAP) col[dst * CAP + s] = (u16)ei[e];
            }
        }
        return;
    }
    if (blockIdx.x < FILLB + SETUPB) {
        // ---- setup: layer weights -> bf16 transposed; gstart ----
        int idx = (blockIdx.x - FILLB) * 256 + tid;
        if (idx < NLAYER * NHID * NHID) {
            int l = idx >> 12, rem = idx & 4095, n = rem >> 6, k = rem & 63;
            wt[l * 8192 + n * 64 + k]        = f2b(W1[l * 4096 + k * 64 + n]);
            wt[l * 8192 + 4096 + n * 64 + k] = f2b(W2[l * 4096 + k * 64 + n]);
            return;
        }
        idx -= NLAYER * NHID * NHID;
        if (idx <= NGRAPHS) {
            if (idx == NGRAPHS) { gstart[NGRAPHS] = NNODES; return; }
            int lo = 0, hi = NNODES;
            while (lo < hi) {
                int mid = (lo + hi) >> 1;
                if (batch[mid] < idx) lo = mid + 1; else hi = mid;
            }
            gstart[idx] = lo;
        }
        return;
    }
    // ---- MFMA input GEMM: z0 = x @ Wt + bt (bf16); W frags from Wt f32 (strided) ----
    int vb = blockIdx.x - FILLB - SETUPB;
    int base = vb * 32;
#pragma unroll
    for (int i = 0; i < 4; ++i) {
        int idx = i * 256 + tid;
        int row = idx >> 5, kq = idx & 31;
        int rc = min(base + row, NNODES - 1);
        float4 v = ((const float4*)(x + (long long)rc * NFEAT))[kq];
        *(uint2*)&sx[row][kq * 4] = pack4(v.x, v.y, v.z, v.w);
    }
    __syncthreads();
    int w = tid >> 6, lane = tid & 63;
    int m = lane & 15, g = lane >> 4;
    int ncol = w * 16 + m;
    bool hiv = (base + 16 < NNODES);
    float bb = bt[ncol];
    f32x4 cl = {bb, bb, bb, bb}, ch = {bb, bb, bb, bb};
    const float* wnf = Wt + ncol;            // column ncol of Wt, stride NHID
#pragma unroll
    for (int s4 = 0; s4 < 4; ++s4) {
        int k0 = s4 * 32 + g * 8;
        union { u16 t[8]; bf8 v; } ub;
#pragma unroll
        for (int i = 0; i < 8; ++i) ub.t[i] = f2b(wnf[(k0 + i) * NHID]);
        bf8 B = ub.v;
        bf8 Al = ldb8(&sx[m][k0]);
        bf8 Ah = ldb8(&sx[16 + m][k0]);
        cl = __builtin_amdgcn_mfma_f32_16x16x32_bf16(Al, B, cl, 0, 0, 0);
        ch = __builtin_amdgcn_mfma_f32_16x16x32_bf16(Ah, B, ch, 0, 0, 0);
    }
    float s1 = cl[0] + cl[1] + cl[2] + cl[3];
    float s2 = cl[0] * cl[0] + cl[1] * cl[1] + cl[2] * cl[2] + cl[3] * cl[3];
    if (hiv) {
        s1 += ch[0] + ch[1] + ch[2] + ch[3];
        s2 += ch[0] * ch[0] + ch[1] * ch[1] + ch[2] * ch[2] + ch[3] * ch[3];
    }
    s1 += __shfl_xor(s1, 16, 64); s1 += __shfl_xor(s1, 32, 64);
    s2 += __shfl_xor(s2, 16, 64); s2 += __shfl_xor(s2, 32, 64);
    if (lane < 16) {
        ps[w * 16 + lane] = s1;
        ps[64 + w * 16 + lane] = s2;
    }
#pragma unroll
    for (int i = 0; i < 4; ++i) {
        zout[(base + g * 4 + i) * NHID + ncol] = f2b(cl[i]);
        if (hiv) zout[(base + 16 + g * 4 + i) * NHID + ncol] = f2b(ch[i]);
    }
    __syncthreads();
    if (tid < 128) partials[vb * 128 + tid] = ps[tid];
}

// ---------------------------------------------------------------- reduce partials -> stats[128]
__global__ __launch_bounds__(256) void k_red(const float* __restrict__ partials,
                                             float* __restrict__ stats, int np) {
    __shared__ float red[4];
    int c = blockIdx.x, t = threadIdx.x;
    float s = 0.f;
    for (int i = t; i < np; i += 256) s += partials[i * 128 + c];
#pragma unroll
    for (int off = 32; off >= 1; off >>= 1) s += __shfl_xor(s, off, 64);
    if ((t & 63) == 0) red[t >> 6] = s;
    __syncthreads();
    if (t == 0) stats[c] = red[0] + red[1] + red[2] + red[3];
}

// ---------------------------------------------------------------- h = relu(bn(z)) streaming
__global__ __launch_bounds__(256) void k_bnh(const u16* __restrict__ z,
                                             const float* __restrict__ stats,
                                             const float* __restrict__ gamma,
                                             const float* __restrict__ beta,
                                             u16* __restrict__ h) {
    int idx = blockIdx.x * 256 + threadIdx.x;
    if (idx >= NNODES * NHID / 8) return;
    int j0 = (idx & 7) * 8;
    uint4 v = ((const uint4*)z)[idx];
    float o[8];
    unp8(o, v);
#pragma unroll
    for (int k = 0; k < 8; ++k) {
        int j = j0 + k;
        float m = stats[j] * (1.0f / NNODES);
        float var = stats[64 + j] * (1.0f / NNODES) - m * m;
        float sc = rsqrtf(var + BN_EPS) * gamma[j];
        o[k] = fmaxf(fmaf(o[k], sc, beta[j] - m * sc), 0.f);
    }
    uint4 w;
    uint2 p0 = pack4(o[0], o[1], o[2], o[3]);
    uint2 p1 = pack4(o[4], o[5], o[6], o[7]);
    w.x = p0.x; w.y = p0.y; w.z = p1.x; w.w = p1.y;
    ((uint4*)h)[idx] = w;
}

// ---------------------------------------------------------------- pool (blocks 0..511) + finalize (blocks 512+), one dispatch
__global__ __launch_bounds__(256) void k_poolfin(const u16* __restrict__ z,
                                                 const float* __restrict__ stats,
                                                 const float* __restrict__ gamma,
                                                 const float* __restrict__ beta,
                                                 const int* __restrict__ gstart,
                                                 const float* __restrict__ poolacc,
                                                 float* __restrict__ out) {
    if (blockIdx.x >= NGRAPHS) {
        int idx = (int)(blockIdx.x - NGRAPHS) * 256 + threadIdx.x;
        if (idx < NLAYER * NGRAPHS * NHID) {
            int g = (idx >> 6) & (NGRAPHS - 1);
            float cnt = (float)(gstart[g + 1] - gstart[g]);
            out[idx] = poolacc[idx] / fmaxf(cnt, 1.0f);
        }
        return;
    }
    __shared__ float4 red[4][16];
    int gph = blockIdx.x;
    int lane = threadIdx.x & 63, w = threadIdx.x >> 6;
    int c = lane & 15, ws = lane >> 4;
    int slot = w * 4 + ws;
    int j0 = c * 4;
    float sc[4], sh[4];
#pragma unroll
    for (int k = 0; k < 4; ++k) {
        int j = j0 + k;
        float m = stats[j] * (1.0f / NNODES);
        float var = stats[64 + j] * (1.0f / NNODES) - m * m;
        sc[k] = rsqrtf(var + BN_EPS) * gamma[j];
        sh[k] = beta[j] - m * sc[k];
    }
    const ushort4* z4 = (const ushort4*)z;
    int s0 = gstart[gph], e0 = gstart[gph + 1];
    float a[4] = {0.f, 0.f, 0.f, 0.f};
    for (int r = s0 + slot; r < e0; r += 16) {
        ushort4 v = z4[r * 16 + c];
        a[0] += fmaxf(fmaf(b2f(v.x), sc[0], sh[0]), 0.f);
        a[1] += fmaxf(fmaf(b2f(v.y), sc[1], sh[1]), 0.f);
        a[2] += fmaxf(fmaf(b2f(v.z), sc[2], sh[2]), 0.f);
        a[3] += fmaxf(fmaf(b2f(v.w), sc[3], sh[3]), 0.f);
    }
#pragma unroll
    for (int k = 0; k < 4; ++k) {
        a[k] += __shfl_xor(a[k], 16, 64);
        a[k] += __shfl_xor(a[k], 32, 64);
    }
    if (lane < 16) red[w][c] = make_float4(a[0], a[1], a[2], a[3]);
    __syncthreads();
    if (threadIdx.x < 16) {
        float4 r0 = red[0][threadIdx.x], r1 = red[1][threadIdx.x];
        float4 r2 = red[2][threadIdx.x], r3 = red[3][threadIdx.x];
        float inv = 1.0f / fmaxf((float)(e0 - s0), 1.0f);
        float* o = &out[NLAYER * NGRAPHS * NHID + gph * NHID + threadIdx.x * 4];
        o[0] = (r0.x + r1.x + r2.x + r3.x) * inv;
        o[1] = (r0.y + r1.y + r2.y + r3.y) * inv;
        o[2] = (r0.z + r1.z + r2.z + r3.z) * inv;
        o[3] = (r0.w + r1.w + r2.w + r3.w) * inv;
    }
}

// ---------------------------------------------------------------- gather + MFMA MLP: 512 threads, 32 nodes/block, 16-deep gather
template <int AFFINE>
__global__ __launch_bounds__(512) void k_mlp(const u16* __restrict__ hin,
                                             const float* __restrict__ stats,
                                             const float* __restrict__ gamma,
                                             const float* __restrict__ beta,
                                             const int* __restrict__ batch,
                                             const int* __restrict__ deg,
                                             const u16* __restrict__ col,
                                             const u16* __restrict__ w1t,
                                             const float* __restrict__ b1,
                                             const u16* __restrict__ w2t,
                                             const float* __restrict__ b2,
                                             u16* __restrict__ zout,
                                             float* __restrict__ partials,
                                             float* __restrict__ poolacc) {
    __shared__ u16 szb[32][PADW];
    __shared__ u16 stb[32][PADW];
    __shared__ float ps2[2][128];
    int tid = threadIdx.x;
    int w = tid >> 6, lane = tid & 63;
    int nq = lane >> 4, c = lane & 15;
    int node = w * 4 + nq;
    int base = blockIdx.x * 32;
    int r = base + node;
    bool rv = (r < NNODES);
    int rc = rv ? r : (NNODES - 1);
    const uint2* h8 = (const uint2*)hin;

    float sc[4], sh[4];
    if (AFFINE) {
#pragma unroll
        for (int k = 0; k < 4; ++k) {
            int j = c * 4 + k;
            float m = stats[j] * (1.0f / NNODES);
            float var = stats[64 + j] * (1.0f / NNODES) - m * m;
            sc[k] = rsqrtf(var + BN_EPS) * gamma[j];
            sh[k] = beta[j] - m * sc[k];
        }
    }

    // self + gather (pure adds); 16-deep unroll (no padding), 4 accumulators
    float acc[4], acc2[4] = {0, 0, 0, 0}, acc3[4] = {0, 0, 0, 0}, acc4[4] = {0, 0, 0, 0};
    float selfh[4];
    {
        uint2 sv = h8[rc * 16 + c];
        unp4(acc, sv);
#pragma unroll
        for (int k = 0; k < 4; ++k)
            selfh[k] = AFFINE ? fmaf(acc[k], sc[k], sh[k]) : acc[k];
    }
    int dd = rv ? min(deg[r], CAP) : 0;
    {
        const u16* cp = col + rc * CAP;
        int t = 0;
        for (; t + 16 <= dd; t += 16) {
            uint4 iva = *(const uint4*)(cp + t);
            uint4 ivb = *(const uint4*)(cp + t + 8);
            int s0 = iva.x & 0xFFFF, s1 = iva.x >> 16;
            int s2 = iva.y & 0xFFFF, s3 = iva.y >> 16;
            int s4 = iva.z & 0xFFFF, s5 = iva.z >> 16;
            int s6 = iva.w & 0xFFFF, s7 = iva.w >> 16;
            int s8 = ivb.x & 0xFFFF, s9 = ivb.x >> 16;
            int sA = ivb.y & 0xFFFF, sB = ivb.y >> 16;
            int sC = ivb.z & 0xFFFF, sD = ivb.z >> 16;
            int sE = ivb.w & 0xFFFF, sF = ivb.w >> 16;
            uint2 v0 = h8[s0 * 16 + c];
            uint2 v1 = h8[s1 * 16 + c];
            uint2 v2 = h8[s2 * 16 + c];
            uint2 v3 = h8[s3 * 16 + c];
            uint2 v4 = h8[s4 * 16 + c];
            uint2 v5 = h8[s5 * 16 + c];
            uint2 v6 = h8[s6 * 16 + c];
            uint2 v7 = h8[s7 * 16 + c];
            uint2 v8 = h8[s8 * 16 + c];
            uint2 v9 = h8[s9 * 16 + c];
            uint2 vA = h8[sA * 16 + c];
            uint2 vB = h8[sB * 16 + c];
            uint2 vC = h8[sC * 16 + c];
            uint2 vD = h8[sD * 16 + c];
            uint2 vE = h8[sE * 16 + c];
            uint2 vF = h8[sF * 16 + c];
            add4(acc, v0);  add4(acc2, v1); add4(acc3, v2); add4(acc4, v3);
            add4(acc, v4);  add4(acc2, v5); add4(acc3, v6); add4(acc4, v7);
            add4(acc, v8);  add4(acc2, v9); add4(acc3, vA); add4(acc4, vB);
            add4(acc, vC);  add4(acc2, vD); add4(acc3, vE); add4(acc4, vF);
        }
        if (t + 8 <= dd) {
            uint4 iv = *(const uint4*)(cp + t);
            int s0 = iv.x & 0xFFFF, s1 = iv.x >> 16;
            int s2 = iv.y & 0xFFFF, s3 = iv.y >> 16;
            int s4 = iv.z & 0xFFFF, s5 = iv.z >> 16;
            int s6 = iv.w & 0xFFFF, s7 = iv.w >> 16;
            uint2 v0 = h8[s0 * 16 + c];
            uint2 v1 = h8[s1 * 16 + c];
            uint2 v2 = h8[s2 * 16 + c];
            uint2 v3 = h8[s3 * 16 + c];
            uint2 v4 = h8[s4 * 16 + c];
            uint2 v5 = h8[s5 * 16 + c];
            uint2 v6 = h8[s6 * 16 + c];
            uint2 v7 = h8[s7 * 16 + c];
            add4(acc, v0); add4(acc2, v1); add4(acc3, v2); add4(acc4, v3);
            add4(acc, v4); add4(acc2, v5); add4(acc3, v6); add4(acc4, v7);
            t += 8;
        }
        if (t + 4 <= dd) {
            uint2 iv = *(const uint2*)(cp + t);
            int s0 = iv.x & 0xFFFF, s1 = iv.x >> 16;
            int s2 = iv.y & 0xFFFF, s3 = iv.y >> 16;
            uint2 v0 = h8[s0 * 16 + c];
            uint2 v1 = h8[s1 * 16 + c];
            uint2 v2 = h8[s2 * 16 + c];
            uint2 v3 = h8[s3 * 16 + c];
            add4(acc, v0); add4(acc2, v1); add4(acc3, v2); add4(acc4, v3);
            t += 4;
        }
        for (; t < dd; ++t) {
            uint2 v0 = h8[(int)cp[t] * 16 + c];
            add4(acc, v0);
        }
    }
    {
        float zv[4];
#pragma unroll
        for (int k = 0; k < 4; ++k) {
            float s = (acc[k] + acc2[k]) + (acc3[k] + acc4[k]);
            zv[k] = AFFINE ? fmaf(s, sc[k], (float)(1 + dd) * sh[k]) : s;
            if (!rv) zv[k] = 0.f;
        }
        *(uint2*)&szb[node][c * 4] = pack4(zv[0], zv[1], zv[2], zv[3]);
    }

    // prefetch W fragments (independent of pool atomics below)
    int m = lane & 15, g = lane >> 4;
    int half = w >> 2, cg = w & 3;
    int ncol = cg * 16 + m;
    const u16* w1n = w1t + ncol * 64;
    const u16* w2n = w2t + ncol * 64;
    bf8 B0 = ldb8g(w1n + g * 8);
    bf8 B1 = ldb8g(w1n + 32 + g * 8);
    bf8 D0 = ldb8g(w2n + g * 8);
    bf8 D1 = ldb8g(w2n + 32 + g * 8);

    // pool atomics: masked shfl reduce over the wave's 4 nodes
    {
        int r0 = base + w * 4;
        int myg = rv ? batch[r] : -1;
        int g_lo = batch[min(r0, NNODES - 1)];
        int g_hi = batch[min(r0 + 3, NNODES - 1)];
        for (int gg = g_lo; gg <= g_hi; ++gg) {
            float v[4];
#pragma unroll
            for (int k = 0; k < 4; ++k) {
                v[k] = (myg == gg) ? selfh[k] : 0.f;
                v[k] += __shfl_xor(v[k], 16, 64);
                v[k] += __shfl_xor(v[k], 32, 64);
            }
            if (lane < 16) {
                float* p = &poolacc[gg * NHID + lane * 4];
#pragma unroll
                for (int k = 0; k < 4; ++k) atomicAdd(p + k, v[k]);
            }
        }
    }
    __syncthreads();   // szb complete

    // ---- MFMA: wave (half, cg) owns rows [half*16,+16) x cols [cg*16,+16) ----
    bool hiv = (base + 16 < NNODES);
    bool halfv = (half == 0) || hiv;
    bf8 A0 = ldb8(&szb[half * 16 + m][g * 8]);
    bf8 A1 = ldb8(&szb[half * 16 + m][32 + g * 8]);
    float bb1 = b1[ncol];
    f32x4 c1 = {bb1, bb1, bb1, bb1};
    c1 = __builtin_amdgcn_mfma_f32_16x16x32_bf16(A0, B0, c1, 0, 0, 0);
    c1 = __builtin_amdgcn_mfma_f32_16x16x32_bf16(A1, B1, c1, 0, 0, 0);
#pragma unroll
    for (int i = 0; i < 4; ++i)
        stb[half * 16 + g * 4 + i][ncol] = f2b(fmaxf(c1[i], 0.f));
    __syncthreads();

    bf8 C0 = ldb8(&stb[half * 16 + m][g * 8]);
    bf8 C1 = ldb8(&stb[half * 16 + m][32 + g * 8]);
    float bb2 = b2[ncol];
    f32x4 e = {bb2, bb2, bb2, bb2};
    e = __builtin_amdgcn_mfma_f32_16x16x32_bf16(C0, D0, e, 0, 0, 0);
    e = __builtin_amdgcn_mfma_f32_16x16x32_bf16(C1, D1, e, 0, 0, 0);

    float s1 = e[0] + e[1] + e[2] + e[3];
    float s2 = e[0] * e[0] + e[1] * e[1] + e[2] * e[2] + e[3] * e[3];
    if (!halfv) { s1 = 0.f; s2 = 0.f; }
    s1 += __shfl_xor(s1, 16, 64); s1 += __shfl_xor(s1, 32, 64);
    s2 += __shfl_xor(s2, 16, 64); s2 += __shfl_xor(s2, 32, 64);
    if (lane < 16) {
        ps2[half][cg * 16 + lane] = s1;
        ps2[half][64 + cg * 16 + lane] = s2;
    }
    if (halfv) {
#pragma unroll
        for (int i = 0; i < 4; ++i)
            zout[(base + half * 16 + g * 4 + i) * NHID + ncol] = f2b(e[i]);
    }
    __syncthreads();
    if (tid < 128) partials[blockIdx.x * 128 + tid] = ps2[0][tid] + ps2[1][tid];
}

// ----------------------------------------------------------------
extern "C" void kernel_launch(void* const* d_in, const int* in_sizes, int n_in,
                              void* d_out, int out_size, void* d_ws, size_t ws_size,
                              hipStream_t stream) {
    const float* x     = (const float*)d_in[0];
    const int*   ei    = (const int*)d_in[1];
    const int*   batch = (const int*)d_in[2];
    const float* Wt    = (const float*)d_in[3];
    const float* bt    = (const float*)d_in[4];
    const float* gt    = (const float*)d_in[5];
    const float* bet   = (const float*)d_in[6];
    const float* W1    = (const float*)d_in[7];
    const float* b1    = (const float*)d_in[8];
    const float* W2    = (const float*)d_in[9];
    const float* b2    = (const float*)d_in[10];
    const float* g     = (const float*)d_in[11];
    const float* be    = (const float*)d_in[12];
    float* out = (float*)d_out;

    u16* A          = (u16*)d_ws;
    u16* B          = A + NNODES * NHID;
    u16* H          = B + NNODES * NHID;
    u16* wt         = H + NNODES * NHID;
    float* partials = (float*)(wt + NLAYER * 2 * NHID * NHID);
    float* stats    = partials + MLPB * 128;
    int* deg        = (int*)(stats + 4 * 128);
    float* poolacc  = (float*)(deg + NNODES);
    u16* col        = (u16*)(poolacc + NLAYER * NGRAPHS * NHID);
    int* gstart     = (int*)(col + NNODES * CAP);

    size_t zbytes = NNODES * sizeof(int) + NLAYER * NGRAPHS * NHID * sizeof(float);
    hipMemsetAsync(deg, 0, zbytes, stream);

    // fused: CSR fill + setup + MFMA input GEMM
    k_buildgemm<<<FILLB + SETUPB + MLPB, 256, 0, stream>>>(
        ei, deg, col, Wt, W1, W2, batch, wt, gstart, x, bt, A, partials);
    k_red<<<128, 256, 0, stream>>>(partials, stats, MLPB);

    // layer 0 (affine shortcut, pool0 fused): A -> B
    k_mlp<1><<<MLPB, 512, 0, stream>>>(A, stats, gt, bet, batch, deg, col,
                                       wt, b1, wt + 4096, b2,
                                       B, partials, poolacc);
    k_red<<<128, 256, 0, stream>>>(partials, stats + 128, MLPB);

    // layer 1: h1 = relu(bn1(z1)); H -> A, pool1
    k_bnh<<<MLPB, 256, 0, stream>>>(B, stats + 128, g, be, H);
    k_mlp<0><<<MLPB, 512, 0, stream>>>(H, stats + 128, g, be, batch, deg, col,
                                       wt + 8192, b1 + NHID, wt + 8192 + 4096, b2 + NHID,
                                       A, partials, poolacc + NGRAPHS * NHID);
    k_red<<<128, 256, 0, stream>>>(partials, stats + 256, MLPB);

    // layer 2: h2 = relu(bn2(z2)); H -> B, pool2
    k_bnh<<<MLPB, 256, 0, stream>>>(A, stats + 256, g + NHID, be + NHID, H);
    k_mlp<0><<<MLPB, 512, 0, stream>>>(H, stats + 256, g + NHID, be + NHID, batch, deg, col,
                                       wt + 16384, b1 + 2 * NHID, wt + 16384 + 4096, b2 + 2 * NHID,
                                       B, partials, poolacc + 2 * NGRAPHS * NHID);
    k_red<<<128, 256, 0, stream>>>(partials, stats + 384, MLPB);

    // stage-3 pool + finalize stages 0..2
    k_poolfin<<<NGRAPHS + (NLAYER * NGRAPHS * NHID + 255) / 256, 256, 0, stream>>>(
        B, stats + 384, g + 2 * NHID, be + 2 * NHID, gstart, poolacc, out);
}

// Round 25
// 182.503 us; speedup vs baseline: 1.1322x; 1.1322x over previous
//
#include <hip/hip_runtime.h>

#define NFEAT   128
#define NHID    64
#define NLAYER  3
#define NNODES  50000
#define NEDGES  800000
#define NGRAPHS 512
#define BN_EPS  1e-5f
#define MLPB    1563          // virtual blocks for gemm/mlp/bnh (ceil(50000/32))
#define CAP     64            // fixed CSR row capacity (max deg ~45 for Poisson(16))
#define PADW    68            // u16 row pad (136B rows, 8B aligned)
#define FILLB   2048          // fill blocks (8 ranges x 256 chunks)
#define SETUPB  51            // setup blocks (wt cvt 12288 + gstart 513)

typedef unsigned short u16;
typedef __attribute__((ext_vector_type(8))) short bf8;     // 8 bf16 (4 VGPRs)
typedef __attribute__((ext_vector_type(4))) float f32x4;

__device__ inline float b2f(u16 v) { return __uint_as_float(((unsigned)v) << 16); }
__device__ inline u16 f2b(float f) {
    unsigned u = __float_as_uint(f);
    return (u16)((u + 0x7FFF + ((u >> 16) & 1)) >> 16);   // RN-even
}
__device__ inline bf8 ldb8(const u16* p) {   // 16B from 8B-aligned LDS
    union { uint2 a[2]; bf8 v; } u;
    u.a[0] = *(const uint2*)p;
    u.a[1] = *(const uint2*)(p + 4);
    return u.v;
}
__device__ inline bf8 ldb8g(const u16* p) {  // 16B from 16B-aligned global
    union { uint4 a; bf8 v; } u;
    u.a = *(const uint4*)p;
    return u.v;
}
__device__ inline void add4(float* a, const uint2 v) {   // a[0..3] += bf16x4
    a[0] += __uint_as_float(v.x << 16);
    a[1] += __uint_as_float(v.x & 0xFFFF0000u);
    a[2] += __uint_as_float(v.y << 16);
    a[3] += __uint_as_float(v.y & 0xFFFF0000u);
}
__device__ inline void unp4(float* a, const uint2 v) {
    a[0] = __uint_as_float(v.x << 16);
    a[1] = __uint_as_float(v.x & 0xFFFF0000u);
    a[2] = __uint_as_float(v.y << 16);
    a[3] = __uint_as_float(v.y & 0xFFFF0000u);
}
__device__ inline void unp8(float* a, const uint4 v) {
    a[0] = __uint_as_float(v.x << 16);
    a[1] = __uint_as_float(v.x & 0xFFFF0000u);
    a[2] = __uint_as_float(v.y << 16);
    a[3] = __uint_as_float(v.y & 0xFFFF0000u);
    a[4] = __uint_as_float(v.z << 16);
    a[5] = __uint_as_float(v.z & 0xFFFF0000u);
    a[6] = __uint_as_float(v.w << 16);
    a[7] = __uint_as_float(v.w & 0xFFFF0000u);
}
__device__ inline uint2 pack4(float a, float b, float c, float d) {
    uint2 r;
    r.x = (unsigned)f2b(a) | ((unsigned)f2b(b) << 16);
    r.y = (unsigned)f2b(c) | ((unsigned)f2b(d) << 16);
    return r;
}

// ---------------------------------------------------------------- build + setup + MFMA input GEMM, one dispatch (no fences)
__global__ __launch_bounds__(256) void k_buildgemm(const int* __restrict__ ei,
                                                   int* __restrict__ deg,
                                                   u16* __restrict__ col,
                                                   const float* __restrict__ Wt,
                                                   const float* __restrict__ W1,
                                                   const float* __restrict__ W2,
                                                   const int* __restrict__ batch,
                                                   u16* __restrict__ wt,
                                                   int* __restrict__ gstart,
                                                   const float* __restrict__ x,
                                                   const float* __restrict__ bt,
                                                   u16* __restrict__ zout,
                                                   float* __restrict__ partials) {
    __shared__ u16 sx[32][132];
    __shared__ float ps[128];
    int tid = threadIdx.x;
    if (blockIdx.x < FILLB) {
        // ---- CSR fill (8x ILP, XCD-range partitioned) ----
        int rangeId = blockIdx.x & 7, chunk = blockIdx.x >> 3;
        int lo = rangeId * (NNODES / 8), hi = lo + (NNODES / 8);
        int ebeg = chunk * (NEDGES / 256), eend = ebeg + (NEDGES / 256);
        int e = ebeg + tid;
        for (; e + 7 * 256 < eend; e += 8 * 256) {
            int d[8];
#pragma unroll
            for (int i = 0; i < 8; ++i) d[i] = ei[NEDGES + e + i * 256];
#pragma unroll
            for (int i = 0; i < 8; ++i) {
                if (d[i] >= lo && d[i] < hi) {
                    int s = atomicAdd(&deg[d[i]], 1);
                    if (s < CAP) col[d[i] * CAP + s] = (u16)ei[e + i * 256];
                }
            }
        }
        for (; e < eend; e += 256) {
            int dst = ei[NEDGES + e];
            if (dst >= lo && dst < hi) {
                int s = atomicAdd(&deg[dst], 1);
                if (s < CAP) col[dst * CAP + s] = (u16)ei[e];
            }
        }
        return;
    }
    if (blockIdx.x < FILLB + SETUPB) {
        // ---- setup: layer weights -> bf16 transposed; gstart ----
        int idx = (blockIdx.x - FILLB) * 256 + tid;
        if (idx < NLAYER * NHID * NHID) {
            int l = idx >> 12, rem = idx & 4095, n = rem >> 6, k = rem & 63;
            wt[l * 8192 + n * 64 + k]        = f2b(W1[l * 4096 + k * 64 + n]);
            wt[l * 8192 + 4096 + n * 64 + k] = f2b(W2[l * 4096 + k * 64 + n]);
            return;
        }
        idx -= NLAYER * NHID * NHID;
        if (idx <= NGRAPHS) {
            if (idx == NGRAPHS) { gstart[NGRAPHS] = NNODES; return; }
            int lo = 0, hi = NNODES;
            while (lo < hi) {
                int mid = (lo + hi) >> 1;
                if (batch[mid] < idx) lo = mid + 1; else hi = mid;
            }
            gstart[idx] = lo;
        }
        return;
    }
    // ---- MFMA input GEMM: z0 = x @ Wt + bt (bf16); W frags from Wt f32 (strided) ----
    int vb = blockIdx.x - FILLB - SETUPB;
    int base = vb * 32;
#pragma unroll
    for (int i = 0; i < 4; ++i) {
        int idx = i * 256 + tid;
        int row = idx >> 5, kq = idx & 31;
        int rc = min(base + row, NNODES - 1);
        float4 v = ((const float4*)(x + (long long)rc * NFEAT))[kq];
        *(uint2*)&sx[row][kq * 4] = pack4(v.x, v.y, v.z, v.w);
    }
    __syncthreads();
    int w = tid >> 6, lane = tid & 63;
    int m = lane & 15, g = lane >> 4;
    int ncol = w * 16 + m;
    bool hiv = (base + 16 < NNODES);
    float bb = bt[ncol];
    f32x4 cl = {bb, bb, bb, bb}, ch = {bb, bb, bb, bb};
    const float* wnf = Wt + ncol;            // column ncol of Wt, stride NHID
#pragma unroll
    for (int s4 = 0; s4 < 4; ++s4) {
        int k0 = s4 * 32 + g * 8;
        union { u16 t[8]; bf8 v; } ub;
#pragma unroll
        for (int i = 0; i < 8; ++i) ub.t[i] = f2b(wnf[(k0 + i) * NHID]);
        bf8 B = ub.v;
        bf8 Al = ldb8(&sx[m][k0]);
        bf8 Ah = ldb8(&sx[16 + m][k0]);
        cl = __builtin_amdgcn_mfma_f32_16x16x32_bf16(Al, B, cl, 0, 0, 0);
        ch = __builtin_amdgcn_mfma_f32_16x16x32_bf16(Ah, B, ch, 0, 0, 0);
    }
    float s1 = cl[0] + cl[1] + cl[2] + cl[3];
    float s2 = cl[0] * cl[0] + cl[1] * cl[1] + cl[2] * cl[2] + cl[3] * cl[3];
    if (hiv) {
        s1 += ch[0] + ch[1] + ch[2] + ch[3];
        s2 += ch[0] * ch[0] + ch[1] * ch[1] + ch[2] * ch[2] + ch[3] * ch[3];
    }
    s1 += __shfl_xor(s1, 16, 64); s1 += __shfl_xor(s1, 32, 64);
    s2 += __shfl_xor(s2, 16, 64); s2 += __shfl_xor(s2, 32, 64);
    if (lane < 16) {
        ps[w * 16 + lane] = s1;
        ps[64 + w * 16 + lane] = s2;
    }
#pragma unroll
    for (int i = 0; i < 4; ++i) {
        zout[(base + g * 4 + i) * NHID + ncol] = f2b(cl[i]);
        if (hiv) zout[(base + 16 + g * 4 + i) * NHID + ncol] = f2b(ch[i]);
    }
    __syncthreads();
    if (tid < 128) partials[vb * 128 + tid] = ps[tid];
}

// ---------------------------------------------------------------- reduce partials -> stats[128]
__global__ __launch_bounds__(256) void k_red(const float* __restrict__ partials,
                                             float* __restrict__ stats, int np) {
    __shared__ float red[4];
    int c = blockIdx.x, t = threadIdx.x;
    float s = 0.f;
    for (int i = t; i < np; i += 256) s += partials[i * 128 + c];
#pragma unroll
    for (int off = 32; off >= 1; off >>= 1) s += __shfl_xor(s, off, 64);
    if ((t & 63) == 0) red[t >> 6] = s;
    __syncthreads();
    if (t == 0) stats[c] = red[0] + red[1] + red[2] + red[3];
}

// ---------------------------------------------------------------- h = relu(bn(z)) streaming
__global__ __launch_bounds__(256) void k_bnh(const u16* __restrict__ z,
                                             const float* __restrict__ stats,
                                             const float* __restrict__ gamma,
                                             const float* __restrict__ beta,
                                             u16* __restrict__ h) {
    int idx = blockIdx.x * 256 + threadIdx.x;
    if (idx >= NNODES * NHID / 8) return;
    int j0 = (idx & 7) * 8;
    uint4 v = ((const uint4*)z)[idx];
    float o[8];
    unp8(o, v);
#pragma unroll
    for (int k = 0; k < 8; ++k) {
        int j = j0 + k;
        float m = stats[j] * (1.0f / NNODES);
        float var = stats[64 + j] * (1.0f / NNODES) - m * m;
        float sc = rsqrtf(var + BN_EPS) * gamma[j];
        o[k] = fmaxf(fmaf(o[k], sc, beta[j] - m * sc), 0.f);
    }
    uint4 w;
    uint2 p0 = pack4(o[0], o[1], o[2], o[3]);
    uint2 p1 = pack4(o[4], o[5], o[6], o[7]);
    w.x = p0.x; w.y = p0.y; w.z = p1.x; w.w = p1.y;
    ((uint4*)h)[idx] = w;
}

// ---------------------------------------------------------------- pool (blocks 0..511) + finalize (blocks 512+), one dispatch
__global__ __launch_bounds__(256) void k_poolfin(const u16* __restrict__ z,
                                                 const float* __restrict__ stats,
                                                 const float* __restrict__ gamma,
                                                 const float* __restrict__ beta,
                                                 const int* __restrict__ gstart,
                                                 const float* __restrict__ poolacc,
                                                 float* __restrict__ out) {
    if (blockIdx.x >= NGRAPHS) {
        int idx = (int)(blockIdx.x - NGRAPHS) * 256 + threadIdx.x;
        if (idx < NLAYER * NGRAPHS * NHID) {
            int g = (idx >> 6) & (NGRAPHS - 1);
            float cnt = (float)(gstart[g + 1] - gstart[g]);
            out[idx] = poolacc[idx] / fmaxf(cnt, 1.0f);
        }
        return;
    }
    __shared__ float4 red[4][16];
    int gph = blockIdx.x;
    int lane = threadIdx.x & 63, w = threadIdx.x >> 6;
    int c = lane & 15, ws = lane >> 4;
    int slot = w * 4 + ws;
    int j0 = c * 4;
    float sc[4], sh[4];
#pragma unroll
    for (int k = 0; k < 4; ++k) {
        int j = j0 + k;
        float m = stats[j] * (1.0f / NNODES);
        float var = stats[64 + j] * (1.0f / NNODES) - m * m;
        sc[k] = rsqrtf(var + BN_EPS) * gamma[j];
        sh[k] = beta[j] - m * sc[k];
    }
    const ushort4* z4 = (const ushort4*)z;
    int s0 = gstart[gph], e0 = gstart[gph + 1];
    float a[4] = {0.f, 0.f, 0.f, 0.f};
    for (int r = s0 + slot; r < e0; r += 16) {
        ushort4 v = z4[r * 16 + c];
        a[0] += fmaxf(fmaf(b2f(v.x), sc[0], sh[0]), 0.f);
        a[1] += fmaxf(fmaf(b2f(v.y), sc[1], sh[1]), 0.f);
        a[2] += fmaxf(fmaf(b2f(v.z), sc[2], sh[2]), 0.f);
        a[3] += fmaxf(fmaf(b2f(v.w), sc[3], sh[3]), 0.f);
    }
#pragma unroll
    for (int k = 0; k < 4; ++k) {
        a[k] += __shfl_xor(a[k], 16, 64);
        a[k] += __shfl_xor(a[k], 32, 64);
    }
    if (lane < 16) red[w][c] = make_float4(a[0], a[1], a[2], a[3]);
    __syncthreads();
    if (threadIdx.x < 16) {
        float4 r0 = red[0][threadIdx.x], r1 = red[1][threadIdx.x];
        float4 r2 = red[2][threadIdx.x], r3 = red[3][threadIdx.x];
        float inv = 1.0f / fmaxf((float)(e0 - s0), 1.0f);
        float* o = &out[NLAYER * NGRAPHS * NHID + gph * NHID + threadIdx.x * 4];
        o[0] = (r0.x + r1.x + r2.x + r3.x) * inv;
        o[1] = (r0.y + r1.y + r2.y + r3.y) * inv;
        o[2] = (r0.z + r1.z + r2.z + r3.z) * inv;
        o[3] = (r0.w + r1.w + r2.w + r3.w) * inv;
    }
}

// ---------------------------------------------------------------- gather + MFMA MLP: 512 threads, 32 nodes/block
template <int AFFINE>
__global__ __launch_bounds__(512) void k_mlp(const u16* __restrict__ hin,
                                             const float* __restrict__ stats,
                                             const float* __restrict__ gamma,
                                             const float* __restrict__ beta,
                                             const int* __restrict__ batch,
                                             const int* __restrict__ deg,
                                             const u16* __restrict__ col,
                                             const u16* __restrict__ w1t,
                                             const float* __restrict__ b1,
                                             const u16* __restrict__ w2t,
                                             const float* __restrict__ b2,
                                             u16* __restrict__ zout,
                                             float* __restrict__ partials,
                                             float* __restrict__ poolacc) {
    __shared__ u16 szb[32][PADW];
    __shared__ u16 stb[32][PADW];
    __shared__ float ps2[2][128];
    int tid = threadIdx.x;
    int w = tid >> 6, lane = tid & 63;
    int nq = lane >> 4, c = lane & 15;
    int node = w * 4 + nq;
    int base = blockIdx.x * 32;
    int r = base + node;
    bool rv = (r < NNODES);
    int rc = rv ? r : (NNODES - 1);
    const uint2* h8 = (const uint2*)hin;

    float sc[4], sh[4];
    if (AFFINE) {
#pragma unroll
        for (int k = 0; k < 4; ++k) {
            int j = c * 4 + k;
            float m = stats[j] * (1.0f / NNODES);
            float var = stats[64 + j] * (1.0f / NNODES) - m * m;
            sc[k] = rsqrtf(var + BN_EPS) * gamma[j];
            sh[k] = beta[j] - m * sc[k];
        }
    }

    float acc[4], acc2[4] = {0, 0, 0, 0};
    float selfh[4];
    {
        uint2 sv = h8[rc * 16 + c];
        unp4(acc, sv);
#pragma unroll
        for (int k = 0; k < 4; ++k)
            selfh[k] = AFFINE ? fmaf(acc[k], sc[k], sh[k]) : acc[k];
    }
    int dd = rv ? min(deg[r], CAP) : 0;
    {
        const u16* cp = col + rc * CAP;
        int t = 0;
        for (; t + 8 <= dd; t += 8) {
            uint4 iv = *(const uint4*)(cp + t);
            int s0 = iv.x & 0xFFFF, s1 = iv.x >> 16;
            int s2 = iv.y & 0xFFFF, s3 = iv.y >> 16;
            int s4 = iv.z & 0xFFFF, s5 = iv.z >> 16;
            int s6 = iv.w & 0xFFFF, s7 = iv.w >> 16;
            uint2 v0 = h8[s0 * 16 + c];
            uint2 v1 = h8[s1 * 16 + c];
            uint2 v2 = h8[s2 * 16 + c];
            uint2 v3 = h8[s3 * 16 + c];
            uint2 v4 = h8[s4 * 16 + c];
            uint2 v5 = h8[s5 * 16 + c];
            uint2 v6 = h8[s6 * 16 + c];
            uint2 v7 = h8[s7 * 16 + c];
            add4(acc, v0); add4(acc2, v1); add4(acc, v2); add4(acc2, v3);
            add4(acc, v4); add4(acc2, v5); add4(acc, v6); add4(acc2, v7);
        }
        if (t + 4 <= dd) {
            uint2 iv = *(const uint2*)(cp + t);
            int s0 = iv.x & 0xFFFF, s1 = iv.x >> 16;
            int s2 = iv.y & 0xFFFF, s3 = iv.y >> 16;
            uint2 v0 = h8[s0 * 16 + c];
            uint2 v1 = h8[s1 * 16 + c];
            uint2 v2 = h8[s2 * 16 + c];
            uint2 v3 = h8[s3 * 16 + c];
            add4(acc, v0); add4(acc2, v1); add4(acc, v2); add4(acc2, v3);
            t += 4;
        }
        for (; t < dd; ++t) {
            uint2 v0 = h8[(int)cp[t] * 16 + c];
            add4(acc, v0);
        }
    }
    {
        float zv[4];
#pragma unroll
        for (int k = 0; k < 4; ++k) {
            float s = acc[k] + acc2[k];
            zv[k] = AFFINE ? fmaf(s, sc[k], (float)(1 + dd) * sh[k]) : s;
            if (!rv) zv[k] = 0.f;
        }
        *(uint2*)&szb[node][c * 4] = pack4(zv[0], zv[1], zv[2], zv[3]);
    }

    // prefetch W fragments (independent of pool atomics below)
    int m = lane & 15, g = lane >> 4;
    int half = w >> 2, cg = w & 3;
    int ncol = cg * 16 + m;
    const u16* w1n = w1t + ncol * 64;
    const u16* w2n = w2t + ncol * 64;
    bf8 B0 = ldb8g(w1n + g * 8);
    bf8 B1 = ldb8g(w1n + 32 + g * 8);
    bf8 D0 = ldb8g(w2n + g * 8);
    bf8 D1 = ldb8g(w2n + 32 + g * 8);

    // pool atomics: masked shfl reduce over the wave's 4 nodes
    {
        int r0 = base + w * 4;
        int myg = rv ? batch[r] : -1;
        int g_lo = batch[min(r0, NNODES - 1)];
        int g_hi = batch[min(r0 + 3, NNODES - 1)];
        for (int gg = g_lo; gg <= g_hi; ++gg) {
            float v[4];
#pragma unroll
            for (int k = 0; k < 4; ++k) {
                v[k] = (myg == gg) ? selfh[k] : 0.f;
                v[k] += __shfl_xor(v[k], 16, 64);
                v[k] += __shfl_xor(v[k], 32, 64);
            }
            if (lane < 16) {
                float* p = &poolacc[gg * NHID + lane * 4];
#pragma unroll
                for (int k = 0; k < 4; ++k) atomicAdd(p + k, v[k]);
            }
        }
    }
    __syncthreads();   // szb complete

    // ---- MFMA: wave (half, cg) owns rows [half*16,+16) x cols [cg*16,+16) ----
    bool hiv = (base + 16 < NNODES);
    bool halfv = (half == 0) || hiv;
    bf8 A0 = ldb8(&szb[half * 16 + m][g * 8]);
    bf8 A1 = ldb8(&szb[half * 16 + m][32 + g * 8]);
    float bb1 = b1[ncol];
    f32x4 c1 = {bb1, bb1, bb1, bb1};
    c1 = __builtin_amdgcn_mfma_f32_16x16x32_bf16(A0, B0, c1, 0, 0, 0);
    c1 = __builtin_amdgcn_mfma_f32_16x16x32_bf16(A1, B1, c1, 0, 0, 0);
#pragma unroll
    for (int i = 0; i < 4; ++i)
        stb[half * 16 + g * 4 + i][ncol] = f2b(fmaxf(c1[i], 0.f));
    __syncthreads();

    bf8 C0 = ldb8(&stb[half * 16 + m][g * 8]);
    bf8 C1 = ldb8(&stb[half * 16 + m][32 + g * 8]);
    float bb2 = b2[ncol];
    f32x4 e = {bb2, bb2, bb2, bb2};
    e = __builtin_amdgcn_mfma_f32_16x16x32_bf16(C0, D0, e, 0, 0, 0);
    e = __builtin_amdgcn_mfma_f32_16x16x32_bf16(C1, D1, e, 0, 0, 0);

    float s1 = e[0] + e[1] + e[2] + e[3];
    float s2 = e[0] * e[0] + e[1] * e[1] + e[2] * e[2] + e[3] * e[3];
    if (!halfv) { s1 = 0.f; s2 = 0.f; }
    s1 += __shfl_xor(s1, 16, 64); s1 += __shfl_xor(s1, 32, 64);
    s2 += __shfl_xor(s2, 16, 64); s2 += __shfl_xor(s2, 32, 64);
    if (lane < 16) {
        ps2[half][cg * 16 + lane] = s1;
        ps2[half][64 + cg * 16 + lane] = s2;
    }
    if (halfv) {
#pragma unroll
        for (int i = 0; i < 4; ++i)
            zout[(base + half * 16 + g * 4 + i) * NHID + ncol] = f2b(e[i]);
    }
    __syncthreads();
    if (tid < 128) partials[blockIdx.x * 128 + tid] = ps2[0][tid] + ps2[1][tid];
}

// ----------------------------------------------------------------
extern "C" void kernel_launch(void* const* d_in, const int* in_sizes, int n_in,
                              void* d_out, int out_size, void* d_ws, size_t ws_size,
                              hipStream_t stream) {
    const float* x     = (const float*)d_in[0];
    const int*   ei    = (const int*)d_in[1];
    const int*   batch = (const int*)d_in[2];
    const float* Wt    = (const float*)d_in[3];
    const float* bt    = (const float*)d_in[4];
    const float* gt    = (const float*)d_in[5];
    const float* bet   = (const float*)d_in[6];
    const float* W1    = (const float*)d_in[7];
    const float* b1    = (const float*)d_in[8];
    const float* W2    = (const float*)d_in[9];
    const float* b2    = (const float*)d_in[10];
    const float* g     = (const float*)d_in[11];
    const float* be    = (const float*)d_in[12];
    float* out = (float*)d_out;

    u16* A          = (u16*)d_ws;
    u16* B          = A + NNODES * NHID;
    u16* H          = B + NNODES * NHID;
    u16* wt         = H + NNODES * NHID;
    float* partials = (float*)(wt + NLAYER * 2 * NHID * NHID);
    float* stats    = partials + MLPB * 128;
    int* deg        = (int*)(stats + 4 * 128);
    float* poolacc  = (float*)(deg + NNODES);
    u16* col        = (u16*)(poolacc + NLAYER * NGRAPHS * NHID);
    int* gstart     = (int*)(col + NNODES * CAP);

    size_t zbytes = NNODES * sizeof(int) + NLAYER * NGRAPHS * NHID * sizeof(float);
    hipMemsetAsync(deg, 0, zbytes, stream);

    // fused: CSR fill + setup + MFMA input GEMM
    k_buildgemm<<<FILLB + SETUPB + MLPB, 256, 0, stream>>>(
        ei, deg, col, Wt, W1, W2, batch, wt, gstart, x, bt, A, partials);
    k_red<<<128, 256, 0, stream>>>(partials, stats, MLPB);

    // layer 0 (affine shortcut, pool0 fused): A -> B
    k_mlp<1><<<MLPB, 512, 0, stream>>>(A, stats, gt, bet, batch, deg, col,
                                       wt, b1, wt + 4096, b2,
                                       B, partials, poolacc);
    k_red<<<128, 256, 0, stream>>>(partials, stats + 128, MLPB);

    // layer 1: h1 = relu(bn1(z1)); H -> A, pool1
    k_bnh<<<MLPB, 256, 0, stream>>>(B, stats + 128, g, be, H);
    k_mlp<0><<<MLPB, 512, 0, stream>>>(H, stats + 128, g, be, batch, deg, col,
                                       wt + 8192, b1 + NHID, wt + 8192 + 4096, b2 + NHID,
                                       A, partials, poolacc + NGRAPHS * NHID);
    k_red<<<128, 256, 0, stream>>>(partials, stats + 256, MLPB);

    // layer 2: h2 = relu(bn2(z2)); H -> B, pool2
    k_bnh<<<MLPB, 256, 0, stream>>>(A, stats + 256, g + NHID, be + NHID, H);
    k_mlp<0><<<MLPB, 512, 0, stream>>>(H, stats + 256, g + NHID, be + NHID, batch, deg, col,
                                       wt + 16384, b1 + 2 * NHID, wt + 16384 + 4096, b2 + 2 * NHID,
                                       B, partials, poolacc + 2 * NGRAPHS * NHID);
    k_red<<<128, 256, 0, stream>>>(partials, stats + 384, MLPB);

    // stage-3 pool + finalize stages 0..2
    k_poolfin<<<NGRAPHS + (NLAYER * NGRAPHS * NHID + 255) / 256, 256, 0, stream>>>(
        B, stats + 384, g + 2 * NHID, be + 2 * NHID, gstart, poolacc, out);
}